// Round 14
// baseline (1220.715 us; speedup 1.0000x reference)
//
#include <hip/hip_runtime.h>
#include <hip/hip_bf16.h>

#define N_NODES 100000
#define PAD_N   100096   // multiple of 128
#define N_EDGES 1600000
#define N_GRAPH 128
#define SCAN_B  1024
#define SCAN_G  ((N_NODES + SCAN_B - 1) / SCAN_B)   // 98

typedef unsigned short u16;
typedef __attribute__((ext_vector_type(4))) float f32x4;
typedef __attribute__((ext_vector_type(8))) short s16x8;

__device__ __forceinline__ float bf2f(u16 u) {
  unsigned int v = ((unsigned int)u) << 16;
  float f; __builtin_memcpy(&f, &v, 4); return f;
}
__device__ __forceinline__ u16 f2bf(float f) {
  unsigned int v; __builtin_memcpy(&v, &f, 4);
  return (u16)((v + 0x7FFFu + ((v >> 16) & 1u)) >> 16);
}
__device__ __forceinline__ void glds16(const u16* g, u16* l) {
  __builtin_amdgcn_global_load_lds(
      (const __attribute__((address_space(1))) unsigned int*)g,
      (__attribute__((address_space(3))) unsigned int*)l, 16, 0, 0);
}

// ---------------- graph preprocessing ----------------
__global__ void k_deg(const int* __restrict__ dst, int* __restrict__ degi) {
  int e = blockIdx.x * 256 + threadIdx.x;
  if (e < N_EDGES) atomicAdd(&degi[dst[e]], 1);
}

__global__ void k_norm(const int* __restrict__ degi, float* __restrict__ nrm) {
  int i = blockIdx.x * 256 + threadIdx.x;
  if (i < N_NODES) {
    int d = degi[i]; if (d < 1) d = 1;
    nrm[i] = 1.0f / sqrtf((float)d);
  }
}

// hierarchical exclusive scan: per-block scan -> scan block sums -> add offsets
__global__ void k_scan1(const int* __restrict__ degi, int* __restrict__ rowptr,
                        int* __restrict__ bsum) {
  __shared__ int sm[SCAN_B];
  int i = blockIdx.x * SCAN_B + threadIdx.x;
  int v = (i < N_NODES) ? degi[i] : 0;
  sm[threadIdx.x] = v;
  __syncthreads();
  for (int off = 1; off < SCAN_B; off <<= 1) {
    int t = (threadIdx.x >= off) ? sm[threadIdx.x - off] : 0;
    __syncthreads();
    sm[threadIdx.x] += t;
    __syncthreads();
  }
  if (i < N_NODES) rowptr[i] = sm[threadIdx.x] - v;   // block-local exclusive
  if (threadIdx.x == SCAN_B - 1) bsum[blockIdx.x] = sm[SCAN_B - 1];
}

__global__ void k_scan2(const int* __restrict__ bsum, int* __restrict__ boff,
                        int* __restrict__ rowptr) {
  __shared__ int sm[128];
  int v = (threadIdx.x < SCAN_G) ? bsum[threadIdx.x] : 0;
  sm[threadIdx.x] = v;
  __syncthreads();
  for (int off = 1; off < 128; off <<= 1) {
    int t = (threadIdx.x >= off) ? sm[threadIdx.x - off] : 0;
    __syncthreads();
    sm[threadIdx.x] += t;
    __syncthreads();
  }
  if (threadIdx.x < SCAN_G) boff[threadIdx.x] = sm[threadIdx.x] - v;
  if (threadIdx.x == 127) rowptr[N_NODES] = sm[127];
}

__global__ void k_scan3(int* __restrict__ rowptr, const int* __restrict__ boff) {
  int i = blockIdx.x * SCAN_B + threadIdx.x;
  if (i < N_NODES) rowptr[i] += boff[blockIdx.x];
}

__global__ void k_scatter(const int* __restrict__ src, const int* __restrict__ dst,
                          const int* __restrict__ rowptr, int* __restrict__ cursor,
                          int* __restrict__ colidx) {
  int e = blockIdx.x * 256 + threadIdx.x;
  if (e >= N_EDGES) return;
  int d = dst[e];
  int p = atomicAdd(&cursor[d], 1);
  colidx[rowptr[d] + p] = src[e];
}

// ---------------- weight transform (bf16, single plane) ----------------
// Logical weights for GEMM over [X0 | X1 | Y=Ahat X1]:
//   rows [0,F): Wa - Wc ; rows [F,2F): Wb ; rows [2F,3F): -2*Wc
// stored transposed [fout][K3] bf16.
__global__ void k_wsplit(const float* __restrict__ W, u16* __restrict__ th,
                         int F, int fout) {
  int K3 = 3 * F;
  int i = blockIdx.x * 256 + threadIdx.x;
  if (i >= K3 * fout) return;
  int k = i / fout, n = i % fout;
  float v;
  if (k < F)          v = W[(size_t)k * fout + n] - W[(size_t)(k + 2 * F) * fout + n];
  else if (k < 2 * F) v = W[(size_t)k * fout + n];
  else                v = -2.0f * W[(size_t)k * fout + n];
  th[(size_t)n * K3 + k] = f2bf(v);
}

__global__ void k_sigcast(const float* __restrict__ s, u16* __restrict__ h) {
  int i = blockIdx.x * 256 + threadIdx.x;
  if (i >= PAD_N * 128) return;
  float v = (i < N_NODES * 128) ? s[i] : 0.f;
  h[i] = f2bf(v);
}

// ---------------- Ahat aggregation (bf16 storage, f32 math) ----------------
template<int VEC>
__global__ void k_ahat_bf(const u16* __restrict__ gh, const float* __restrict__ nrm,
                          const int* __restrict__ rowptr, const int* __restrict__ colidx,
                          u16* __restrict__ oh, int F, int base, int nrows, float alpha) {
  int nl = (blockIdx.x * blockDim.x + threadIdx.x) >> 6;
  int lane = threadIdx.x & 63;
  if (nl >= nrows) return;
  int node = base + nl;
  int fo = lane * VEC;
  float res[VEC];
  if (node < N_NODES) {
    float acc[VEC];
#pragma unroll
    for (int v = 0; v < VEC; ++v) acc[v] = 0.f;
    int e0 = rowptr[node], e1 = rowptr[node + 1];
    int e = e0;
    for (; e + 8 <= e1; e += 8) {
      int ss[8]; float nn[8];
#pragma unroll
      for (int j = 0; j < 8; ++j) ss[j] = colidx[e + j];
#pragma unroll
      for (int j = 0; j < 8; ++j) nn[j] = nrm[ss[j]];
      if constexpr (VEC == 2) {
        unsigned int uu[8];
#pragma unroll
        for (int j = 0; j < 8; ++j) uu[j] = *(const unsigned int*)(gh + (size_t)ss[j] * F + fo);
#pragma unroll
        for (int j = 0; j < 8; ++j) {
          acc[0] += bf2f((u16)uu[j]) * nn[j];
          acc[1] += bf2f((u16)(uu[j] >> 16)) * nn[j];
        }
      } else {
        uint2 uu[8];
#pragma unroll
        for (int j = 0; j < 8; ++j) uu[j] = *(const uint2*)(gh + (size_t)ss[j] * F + fo);
#pragma unroll
        for (int j = 0; j < 8; ++j) {
          acc[0] += bf2f((u16)uu[j].x) * nn[j];
          acc[1] += bf2f((u16)(uu[j].x >> 16)) * nn[j];
          acc[2] += bf2f((u16)uu[j].y) * nn[j];
          acc[3] += bf2f((u16)(uu[j].y >> 16)) * nn[j];
        }
      }
    }
    for (; e + 4 <= e1; e += 4) {
      int ss[4]; float nn[4];
#pragma unroll
      for (int j = 0; j < 4; ++j) ss[j] = colidx[e + j];
#pragma unroll
      for (int j = 0; j < 4; ++j) nn[j] = nrm[ss[j]];
      if constexpr (VEC == 2) {
        unsigned int uu[4];
#pragma unroll
        for (int j = 0; j < 4; ++j) uu[j] = *(const unsigned int*)(gh + (size_t)ss[j] * F + fo);
#pragma unroll
        for (int j = 0; j < 4; ++j) {
          acc[0] += bf2f((u16)uu[j]) * nn[j];
          acc[1] += bf2f((u16)(uu[j] >> 16)) * nn[j];
        }
      } else {
        uint2 uu[4];
#pragma unroll
        for (int j = 0; j < 4; ++j) uu[j] = *(const uint2*)(gh + (size_t)ss[j] * F + fo);
#pragma unroll
        for (int j = 0; j < 4; ++j) {
          acc[0] += bf2f((u16)uu[j].x) * nn[j];
          acc[1] += bf2f((u16)(uu[j].x >> 16)) * nn[j];
          acc[2] += bf2f((u16)uu[j].y) * nn[j];
          acc[3] += bf2f((u16)(uu[j].y >> 16)) * nn[j];
        }
      }
    }
    for (; e < e1; ++e) {
      int s = colidx[e];
      float ns = nrm[s];
      const u16* ph = gh + (size_t)s * F + fo;
      if constexpr (VEC == 2) {
        unsigned int uh = *(const unsigned int*)ph;
        acc[0] += bf2f((u16)uh) * ns;
        acc[1] += bf2f((u16)(uh >> 16)) * ns;
      } else {
        uint2 uh = *(const uint2*)ph;
        acc[0] += bf2f((u16)uh.x) * ns;
        acc[1] += bf2f((u16)(uh.x >> 16)) * ns;
        acc[2] += bf2f((u16)uh.y) * ns;
        acc[3] += bf2f((u16)(uh.y >> 16)) * ns;
      }
    }
    float sc2 = alpha * nrm[node];
#pragma unroll
    for (int v = 0; v < VEC; ++v) res[v] = sc2 * acc[v];
  } else {
#pragma unroll
    for (int v = 0; v < VEC; ++v) res[v] = 0.f;
  }
  u16* po = oh + (size_t)nl * F + fo;
  if constexpr (VEC == 2) {
    *(unsigned int*)po = (unsigned int)f2bf(res[0]) | ((unsigned int)f2bf(res[1]) << 16);
  } else {
    uint2 w;
    w.x = (unsigned int)f2bf(res[0]) | ((unsigned int)f2bf(res[1]) << 16);
    w.y = (unsigned int)f2bf(res[2]) | ((unsigned int)f2bf(res[3]) << 16);
    *(uint2*)po = w;
  }
}

// ======== coalesced staging layout (both GEMMs) ========
// LDS tile: [idx][32] u16 -- one 64B line per row/col. Global source is
// pre-swizzled (quarter (tid&3)^((idx>>1)&3)) so 4 consecutive lanes read one
// cache line; ds_read applies the same XOR: slot = kq ^ ((li>>1)&3). 2-way
// bank alias only (free, m136).
//
// ======== one-barrier K-step (both GEMMs) ========
// Per step: counted vmcnt publishes stage t -> barrier -> issue stage(t+2)
// into the buffer consumed at step t-1 -> plain C++ ds_reads + MFMA with NO
// forced lgkm drain: the compiler interleaves fine-grained lgkmcnt waits with
// the MFMA cluster (m97/m233). Safe because every loaded register is consumed
// by an MFMA before the next barrier, which retires the FIFO DS queue before
// the overwriting stage can issue.

// ---------------- MFMA GEMM (BN=128) ----------------
template<bool POOL>
__launch_bounds__(512, 4)
__global__ void k_gemm_mfma(const u16* __restrict__ A0, const u16* __restrict__ A1,
                            const u16* __restrict__ A2, int F,
                            const u16* __restrict__ Bth,
                            const float* __restrict__ bias, u16* __restrict__ O,
                            float* __restrict__ hg, const int* __restrict__ gid,
                            int fout, int nrows) {
  __shared__ u16 As[3][128][32];
  __shared__ u16 Bs[3][128][32];
  const int tid = threadIdx.x;
  const int lane = tid & 63, wid = tid >> 6;
  const int wm = wid >> 2, wn = wid & 3;          // 2x4 waves, 64x32 each
  const int row0 = blockIdx.y * 128, col0 = blockIdx.x * 128;
  const int K3 = 3 * F;
  const int li = lane & 15, kq = lane >> 4;
  const int sidx = tid >> 2;                      // staged row/col index
  const int skg = (tid & 3) ^ ((sidx >> 1) & 3);  // pre-swizzled 16B quarter
  const size_t dso = (size_t)wid * 512;           // wave-uniform LDS base (u16)
  const int slot = (kq ^ ((li >> 1) & 3)) * 8;    // ds_read-side swizzle

  auto stage = [&](int t, int b) {
    int k0 = t * 32;
    const u16* S; int kk;
    if (k0 < F)          { S = A0; kk = k0; }
    else if (k0 < 2 * F) { S = A1; kk = k0 - F; }
    else                 { S = A2; kk = k0 - 2 * F; }
    glds16(S + (size_t)(row0 + sidx) * F + (kk + skg * 8), &As[b][0][0] + dso);
    glds16(Bth + (size_t)(col0 + sidx) * K3 + (k0 + skg * 8), &Bs[b][0][0] + dso);
  };

  f32x4 acc[4][2];
#pragma unroll
  for (int m = 0; m < 4; ++m)
#pragma unroll
    for (int n = 0; n < 2; ++n) acc[m][n] = (f32x4){0.f, 0.f, 0.f, 0.f};

  const int NT = K3 / 32;                         // 12 or 24
  stage(0, 0);
  stage(1, 1);
  for (int t = 0; t < NT; ++t) {
    if (t + 1 < NT) asm volatile("s_waitcnt vmcnt(2)" ::: "memory");
    else            asm volatile("s_waitcnt vmcnt(0)" ::: "memory");
    __builtin_amdgcn_sched_barrier(0);
    __builtin_amdgcn_s_barrier();                 // everyone's stage-t visible
    const int cb = t % 3;
    if (t + 2 < NT) stage(t + 2, (t + 2) % 3);    // refills buf consumed at t-1
    s16x8 a[4], bh[2];
#pragma unroll
    for (int m = 0; m < 4; ++m)
      a[m] = *(const s16x8*)&As[cb][wm * 64 + m * 16 + li][slot];
#pragma unroll
    for (int n = 0; n < 2; ++n)
      bh[n] = *(const s16x8*)&Bs[cb][wn * 32 + n * 16 + li][slot];
    __builtin_amdgcn_s_setprio(1);                // compiler schedules lgkm waits
#pragma unroll
    for (int m = 0; m < 4; ++m)
#pragma unroll
      for (int n = 0; n < 2; ++n)
        acc[m][n] = __builtin_amdgcn_mfma_f32_16x16x32_bf16(a[m], bh[n], acc[m][n], 0, 0, 0);
    __builtin_amdgcn_s_setprio(0);
  }

  if (!POOL) {
#pragma unroll
    for (int m = 0; m < 4; ++m) {
      int rbase = row0 + wm * 64 + m * 16 + kq * 4;
#pragma unroll
      for (int n = 0; n < 2; ++n) {
        int col = col0 + wn * 32 + n * 16 + li;
        float bi = bias[col];
#pragma unroll
        for (int r2 = 0; r2 < 4; ++r2) {
          int rr = rbase + r2;
          if (rr < nrows)
            O[(size_t)rr * fout + col] = f2bf(fmaxf(acc[m][n][r2] + bi, 0.f));
        }
      }
    }
  } else {
#pragma unroll
    for (int m = 0; m < 4; ++m) {
      int rbase = row0 + wm * 64 + m * 16 + kq * 4;
      int g4[4];
#pragma unroll
      for (int r2 = 0; r2 < 4; ++r2) {
        int rr = rbase + r2;
        g4[r2] = (rr < nrows) ? gid[rr] : -1;
      }
#pragma unroll
      for (int n = 0; n < 2; ++n) {
        int col = col0 + wn * 32 + n * 16 + li;
        float bi = bias[col];
        float sum = 0.f; int curg = g4[0];
#pragma unroll
        for (int r2 = 0; r2 < 4; ++r2) {
          if (g4[r2] != curg) {
            if (curg >= 0) atomicAdd(&hg[curg * 512 + col], sum);
            sum = 0.f; curg = g4[r2];
          }
          if (g4[r2] >= 0) sum += fmaxf(acc[m][n][r2] + bi, 0.f);
        }
        if (curg >= 0) atomicAdd(&hg[curg * 512 + col], sum);
      }
    }
  }
}

// ---------------- MFMA GEMM wide (BN=256, one-barrier K-step) ----------------
template<bool POOL>
__launch_bounds__(512, 4)
__global__ void k_gemm_wide(const u16* __restrict__ A0, const u16* __restrict__ A1,
                            const u16* __restrict__ A2, int F,
                            const u16* __restrict__ Bth,
                            const float* __restrict__ bias, u16* __restrict__ O,
                            float* __restrict__ hg, const int* __restrict__ gid,
                            int fout, int nrows) {
  __shared__ u16 As[3][128][32];   // 24 KB
  __shared__ u16 Bs[3][256][32];   // 48 KB
  const int tid = threadIdx.x;
  const int lane = tid & 63, wid = tid >> 6;
  const int wm = wid >> 2, wn = wid & 3;          // 2x4 waves, 64x64 each
  const int row0 = blockIdx.y * 128, col0 = blockIdx.x * 256;
  const int K3 = 3 * F;
  const int li = lane & 15, kq = lane >> 4;
  const int sidx = tid >> 2;
  const int skg = (tid & 3) ^ ((sidx >> 1) & 3);
  const size_t dsoA = (size_t)wid * 512;          // wave-uniform (u16)
  const int slot = (kq ^ ((li >> 1) & 3)) * 8;

  auto stage = [&](int t, int b) {
    int k0 = t * 32;
    const u16* S; int kk;
    if (k0 < F)          { S = A0; kk = k0; }
    else if (k0 < 2 * F) { S = A1; kk = k0 - F; }
    else                 { S = A2; kk = k0 - 2 * F; }
    glds16(S + (size_t)(row0 + sidx) * F + (kk + skg * 8), &As[b][0][0] + dsoA);
#pragma unroll
    for (int r = 0; r < 2; ++r) {
      int s = r * 512 + tid;
      int col = s >> 2;
      int kgB = (s & 3) ^ ((col >> 1) & 3);
      glds16(Bth + (size_t)(col0 + col) * K3 + (k0 + kgB * 8),
             &Bs[b][0][0] + (size_t)(r * 512 + wid * 64) * 8);
    }
  };

  f32x4 acc[4][4];
#pragma unroll
  for (int m = 0; m < 4; ++m)
#pragma unroll
    for (int n = 0; n < 4; ++n) acc[m][n] = (f32x4){0.f, 0.f, 0.f, 0.f};

  const int NT = K3 / 32;                         // 12 or 24
  stage(0, 0);
  stage(1, 1);
  for (int t = 0; t < NT; ++t) {
    if (t + 1 < NT) asm volatile("s_waitcnt vmcnt(3)" ::: "memory");
    else            asm volatile("s_waitcnt vmcnt(0)" ::: "memory");
    __builtin_amdgcn_sched_barrier(0);
    __builtin_amdgcn_s_barrier();                 // everyone's stage-t visible
    const int cb = t % 3;
    if (t + 2 < NT) stage(t + 2, (t + 2) % 3);    // refills buf consumed at t-1
    s16x8 a[4], b[4];
#pragma unroll
    for (int m = 0; m < 4; ++m)
      a[m] = *(const s16x8*)&As[cb][wm * 64 + m * 16 + li][slot];
#pragma unroll
    for (int n = 0; n < 4; ++n)
      b[n] = *(const s16x8*)&Bs[cb][wn * 64 + n * 16 + li][slot];
    __builtin_amdgcn_s_setprio(1);                // compiler schedules lgkm waits
#pragma unroll
    for (int m = 0; m < 4; ++m)
#pragma unroll
      for (int n = 0; n < 4; ++n)
        acc[m][n] = __builtin_amdgcn_mfma_f32_16x16x32_bf16(a[m], b[n], acc[m][n], 0, 0, 0);
    __builtin_amdgcn_s_setprio(0);
  }

  if (!POOL) {
#pragma unroll
    for (int m = 0; m < 4; ++m) {
      int rbase = row0 + wm * 64 + m * 16 + kq * 4;
#pragma unroll
      for (int n = 0; n < 4; ++n) {
        int col = col0 + wn * 64 + n * 16 + li;
        float bi = bias[col];
#pragma unroll
        for (int r2 = 0; r2 < 4; ++r2) {
          int rr = rbase + r2;
          if (rr < nrows)
            O[(size_t)rr * fout + col] = f2bf(fmaxf(acc[m][n][r2] + bi, 0.f));
        }
      }
    }
  } else {
#pragma unroll
    for (int m = 0; m < 4; ++m) {
      int rbase = row0 + wm * 64 + m * 16 + kq * 4;
      int g4[4];
#pragma unroll
      for (int r2 = 0; r2 < 4; ++r2) {
        int rr = rbase + r2;
        g4[r2] = (rr < nrows) ? gid[rr] : -1;
      }
#pragma unroll
      for (int n = 0; n < 4; ++n) {
        int col = col0 + wn * 64 + n * 16 + li;
        float bi = bias[col];
        float sum = 0.f; int curg = g4[0];
#pragma unroll
        for (int r2 = 0; r2 < 4; ++r2) {
          if (g4[r2] != curg) {
            if (curg >= 0) atomicAdd(&hg[curg * 512 + col], sum);
            sum = 0.f; curg = g4[r2];
          }
          if (g4[r2] >= 0) sum += fmaxf(acc[m][n][r2] + bi, 0.f);
        }
        if (curg >= 0) atomicAdd(&hg[curg * 512 + col], sum);
      }
    }
  }
}

// ---------------- MLP head ----------------
__global__ void k_mlp(const float* __restrict__ hg, const float* __restrict__ Wm1,
                      const float* __restrict__ bm1, const float* __restrict__ Wm2,
                      const float* __restrict__ bm2, float* __restrict__ outp) {
  __shared__ float lh[512];
  __shared__ float lt[512];
  int g = blockIdx.x, t = threadIdx.x;
  lh[t] = hg[g * 512 + t];
  __syncthreads();
  float s = bm1[t];
  for (int k = 0; k < 512; ++k) s += lh[k] * Wm1[k * 512 + t];
  lt[t] = fmaxf(s, 0.f);
  __syncthreads();
  if (t < 10) {
    float s2 = bm2[t];
    for (int j = 0; j < 512; ++j) s2 += lt[j] * Wm2[j * 10 + t];
    outp[g * 10 + t] = s2;
  }
}

// ---------------- launch ----------------
extern "C" void kernel_launch(void* const* d_in, const int* in_sizes, int n_in,
                              void* d_out, int out_size, void* d_ws, size_t ws_size,
                              hipStream_t stream) {
  (void)in_sizes; (void)n_in; (void)out_size;
  const float* signal = (const float*)d_in[0];
  const float* W0 = (const float*)d_in[1];  const float* b0 = (const float*)d_in[2];
  const float* W1 = (const float*)d_in[3];  const float* b1 = (const float*)d_in[4];
  const float* W2 = (const float*)d_in[5];  const float* b2 = (const float*)d_in[6];
  const float* W3 = (const float*)d_in[7];  const float* b3 = (const float*)d_in[8];
  const float* Wm1 = (const float*)d_in[9];  const float* bm1 = (const float*)d_in[10];
  const float* Wm2 = (const float*)d_in[11]; const float* bm2 = (const float*)d_in[12];
  const int* src = (const int*)d_in[13];
  const int* dst = (const int*)d_in[14];
  const int* gid = (const int*)d_in[15];
  float* outp = (float*)d_out;

  char* ws = (char*)d_ws;
  size_t off = 0;
  auto alloc = [&](size_t b) -> void* {
    void* p = ws + off;
    off = (off + b + 255) & ~(size_t)255;
    return p;
  };
  // fixed footprint ~130 MB (+51 MB QY when ws allows; proven in rounds 11-13)
  int* degi    = (int*)alloc((size_t)N_NODES * 4);
  float* nrm   = (float*)alloc((size_t)N_NODES * 4);
  int* rowptr  = (int*)alloc((size_t)(N_NODES + 1) * 4);
  int* cursor  = (int*)alloc((size_t)N_NODES * 4);
  int* bsum    = (int*)alloc((size_t)SCAN_G * 4);
  int* boff    = (int*)alloc((size_t)SCAN_G * 4);
  int* colidx  = (int*)alloc((size_t)N_EDGES * 4);
  float* hg    = (float*)alloc((size_t)N_GRAPH * 512 * 4);
  u16* Wth0 = (u16*)alloc((size_t)384 * 128 * 2);
  u16* Wth1 = (u16*)alloc((size_t)384 * 128 * 2);
  u16* Wth2 = (u16*)alloc((size_t)384 * 256 * 2);
  u16* Wth3 = (u16*)alloc((size_t)768 * 512 * 2);
  u16* QA = (u16*)alloc((size_t)PAD_N * 256 * 2);   // L1 out / L2 in / L3 out / L4 in
  u16* QB = (u16*)alloc((size_t)PAD_N * 128 * 2);   // sig / L2 out / L3 in / L4 Y-chunk
  u16* QX = (u16*)alloc((size_t)PAD_N * 256 * 2);   // X1 (+Y in 2nd half for F=128)
  const size_t yneed = (size_t)PAD_N * 256 * 2;
  u16* QY = nullptr;
  if (ws_size > off && ws_size - off >= yneed + 512) QY = (u16*)alloc(yneed);

  hipMemsetAsync(degi, 0, (size_t)N_NODES * 4, stream);
  hipMemsetAsync(cursor, 0, (size_t)N_NODES * 4, stream);
  hipMemsetAsync(hg, 0, (size_t)N_GRAPH * 512 * 4, stream);

  k_deg<<<(N_EDGES + 255) / 256, 256, 0, stream>>>(dst, degi);
  k_norm<<<(N_NODES + 255) / 256, 256, 0, stream>>>(degi, nrm);
  k_scan1<<<SCAN_G, SCAN_B, 0, stream>>>(degi, rowptr, bsum);
  k_scan2<<<1, 128, 0, stream>>>(bsum, boff, rowptr);
  k_scan3<<<SCAN_G, SCAN_B, 0, stream>>>(rowptr, boff);
  k_scatter<<<(N_EDGES + 255) / 256, 256, 0, stream>>>(src, dst, rowptr, cursor, colidx);

  k_wsplit<<<(384 * 128 + 255) / 256, 256, 0, stream>>>(W0, Wth0, 128, 128);
  k_wsplit<<<(384 * 128 + 255) / 256, 256, 0, stream>>>(W1, Wth1, 128, 128);
  k_wsplit<<<(384 * 256 + 255) / 256, 256, 0, stream>>>(W2, Wth2, 128, 256);
  k_wsplit<<<(768 * 512 + 255) / 256, 256, 0, stream>>>(W3, Wth3, 256, 512);
  k_sigcast<<<(PAD_N * 128 + 255) / 256, 256, 0, stream>>>(signal, QB);

  const int gfull = (PAD_N + 3) / 4;   // ahat grid, 4 nodes per 256-thread block

  // ---- layers 1-2 (F=128, fout=128) ----
  u16* X1h = QX;
  u16* Yh  = QX + (size_t)PAD_N * 128;
  auto layer128 = [&](const u16* in, const u16* wth, const float* bias, u16* outb) {
    k_ahat_bf<2><<<gfull, 256, 0, stream>>>(in,  nrm, rowptr, colidx, X1h, 128, 0, PAD_N, -1.f);
    k_ahat_bf<2><<<gfull, 256, 0, stream>>>(X1h, nrm, rowptr, colidx, Yh,  128, 0, PAD_N,  1.f);
    dim3 gg(1, PAD_N / 128);
    k_gemm_mfma<false><<<gg, 512, 0, stream>>>(in, X1h, Yh, 128, wth, bias,
                                               outb, nullptr, nullptr, 128, N_NODES);
  };
  layer128(QB, Wth0, b0, QA);
  layer128(QA, Wth1, b1, QB);

  // ---- layer 3 (F=128, fout=256): wide kernel, single col-block ----
  k_ahat_bf<2><<<gfull, 256, 0, stream>>>(QB,  nrm, rowptr, colidx, X1h, 128, 0, PAD_N, -1.f);
  k_ahat_bf<2><<<gfull, 256, 0, stream>>>(X1h, nrm, rowptr, colidx, Yh,  128, 0, PAD_N,  1.f);
  {
    dim3 gg(1, PAD_N / 128);
    k_gemm_wide<false><<<gg, 512, 0, stream>>>(QB, X1h, Yh, 128, Wth2, b2,
                                               QA, nullptr, nullptr, 256, N_NODES);
  }

  // ---- layer 4 (F=256, fout=512, pooled) ----
  k_ahat_bf<4><<<gfull, 256, 0, stream>>>(QA, nrm, rowptr, colidx, QX, 256, 0, PAD_N, -1.f);
  if (QY != nullptr) {
    k_ahat_bf<4><<<gfull, 256, 0, stream>>>(QX, nrm, rowptr, colidx, QY, 256, 0, PAD_N, 1.f);
    dim3 gg(2, PAD_N / 128);
    k_gemm_wide<true><<<gg, 512, 0, stream>>>(QA, QX, QY, 256, Wth3, b3,
                                              nullptr, hg, gid, 512, N_NODES);
  } else {
    const int CH4 = 50048;
    for (int base = 0; base < N_NODES; base += CH4) {
      int nr = (N_NODES - base < CH4) ? (N_NODES - base) : CH4;
      k_ahat_bf<4><<<(nr + 3) / 4, 256, 0, stream>>>(QX, nrm, rowptr, colidx, QB,
                                                     256, base, nr, 1.f);
      dim3 gg(4, (nr + 127) / 128);
      k_gemm_mfma<true><<<gg, 512, 0, stream>>>(
          QA + (size_t)base * 256, QX + (size_t)base * 256, QB, 256,
          Wth3, b3, nullptr, hg, gid + base, 512, nr);
    }
  }

  k_mlp<<<N_GRAPH, 512, 0, stream>>>(hg, Wm1, bm1, Wm2, bm2, outp);
}

// Round 15
// 1144.721 us; speedup vs baseline: 1.0664x; 1.0664x over previous
//
#include <hip/hip_runtime.h>
#include <hip/hip_bf16.h>

#define N_NODES 100000
#define PAD_N   100096   // multiple of 128
#define N_EDGES 1600000
#define N_GRAPH 128
#define SCAN_B  1024
#define SCAN_G  ((N_NODES + SCAN_B - 1) / SCAN_B)   // 98

typedef unsigned short u16;
typedef __attribute__((ext_vector_type(4))) float f32x4;
typedef __attribute__((ext_vector_type(8))) short s16x8;

__device__ __forceinline__ float bf2f(u16 u) {
  unsigned int v = ((unsigned int)u) << 16;
  float f; __builtin_memcpy(&f, &v, 4); return f;
}
__device__ __forceinline__ u16 f2bf(float f) {
  unsigned int v; __builtin_memcpy(&v, &f, 4);
  return (u16)((v + 0x7FFFu + ((v >> 16) & 1u)) >> 16);
}
__device__ __forceinline__ void glds16(const u16* g, u16* l) {
  __builtin_amdgcn_global_load_lds(
      (const __attribute__((address_space(1))) unsigned int*)g,
      (__attribute__((address_space(3))) unsigned int*)l, 16, 0, 0);
}

// ---------------- graph preprocessing ----------------
__global__ void k_deg(const int* __restrict__ dst, int* __restrict__ degi) {
  int e = blockIdx.x * 256 + threadIdx.x;
  if (e < N_EDGES) atomicAdd(&degi[dst[e]], 1);
}

__global__ void k_norm(const int* __restrict__ degi, float* __restrict__ nrm) {
  int i = blockIdx.x * 256 + threadIdx.x;
  if (i < N_NODES) {
    int d = degi[i]; if (d < 1) d = 1;
    nrm[i] = 1.0f / sqrtf((float)d);
  }
}

// hierarchical exclusive scan: per-block scan -> scan block sums -> add offsets
__global__ void k_scan1(const int* __restrict__ degi, int* __restrict__ rowptr,
                        int* __restrict__ bsum) {
  __shared__ int sm[SCAN_B];
  int i = blockIdx.x * SCAN_B + threadIdx.x;
  int v = (i < N_NODES) ? degi[i] : 0;
  sm[threadIdx.x] = v;
  __syncthreads();
  for (int off = 1; off < SCAN_B; off <<= 1) {
    int t = (threadIdx.x >= off) ? sm[threadIdx.x - off] : 0;
    __syncthreads();
    sm[threadIdx.x] += t;
    __syncthreads();
  }
  if (i < N_NODES) rowptr[i] = sm[threadIdx.x] - v;   // block-local exclusive
  if (threadIdx.x == SCAN_B - 1) bsum[blockIdx.x] = sm[SCAN_B - 1];
}

__global__ void k_scan2(const int* __restrict__ bsum, int* __restrict__ boff,
                        int* __restrict__ rowptr) {
  __shared__ int sm[128];
  int v = (threadIdx.x < SCAN_G) ? bsum[threadIdx.x] : 0;
  sm[threadIdx.x] = v;
  __syncthreads();
  for (int off = 1; off < 128; off <<= 1) {
    int t = (threadIdx.x >= off) ? sm[threadIdx.x - off] : 0;
    __syncthreads();
    sm[threadIdx.x] += t;
    __syncthreads();
  }
  if (threadIdx.x < SCAN_G) boff[threadIdx.x] = sm[threadIdx.x] - v;
  if (threadIdx.x == 127) rowptr[N_NODES] = sm[127];
}

__global__ void k_scan3(int* __restrict__ rowptr, const int* __restrict__ boff) {
  int i = blockIdx.x * SCAN_B + threadIdx.x;
  if (i < N_NODES) rowptr[i] += boff[blockIdx.x];
}

__global__ void k_scatter(const int* __restrict__ src, const int* __restrict__ dst,
                          const int* __restrict__ rowptr, int* __restrict__ cursor,
                          int* __restrict__ colidx) {
  int e = blockIdx.x * 256 + threadIdx.x;
  if (e >= N_EDGES) return;
  int d = dst[e];
  int p = atomicAdd(&cursor[d], 1);
  colidx[rowptr[d] + p] = src[e];
}

// ---------------- weight transform (bf16, single plane) ----------------
// Logical weights for GEMM over [X0 | X1 | Y=Ahat X1]:
//   rows [0,F): Wa - Wc ; rows [F,2F): Wb ; rows [2F,3F): -2*Wc
// stored transposed [fout][K3] bf16.
__global__ void k_wsplit(const float* __restrict__ W, u16* __restrict__ th,
                         int F, int fout) {
  int K3 = 3 * F;
  int i = blockIdx.x * 256 + threadIdx.x;
  if (i >= K3 * fout) return;
  int k = i / fout, n = i % fout;
  float v;
  if (k < F)          v = W[(size_t)k * fout + n] - W[(size_t)(k + 2 * F) * fout + n];
  else if (k < 2 * F) v = W[(size_t)k * fout + n];
  else                v = -2.0f * W[(size_t)k * fout + n];
  th[(size_t)n * K3 + k] = f2bf(v);
}

__global__ void k_sigcast(const float* __restrict__ s, u16* __restrict__ h) {
  int i = blockIdx.x * 256 + threadIdx.x;
  if (i >= PAD_N * 128) return;
  float v = (i < N_NODES * 128) ? s[i] : 0.f;
  h[i] = f2bf(v);
}

// ---------------- Ahat aggregation (bf16 storage, f32 math) ----------------
// edge bounds are wave-uniform -> readfirstlane makes them SGPR so the
// colidx/nrm loads can scalarize (frees VMEM issue slots).
template<int VEC>
__global__ void k_ahat_bf(const u16* __restrict__ gh, const float* __restrict__ nrm,
                          const int* __restrict__ rowptr, const int* __restrict__ colidx,
                          u16* __restrict__ oh, int F, int base, int nrows, float alpha) {
  int nl = (blockIdx.x * blockDim.x + threadIdx.x) >> 6;
  int lane = threadIdx.x & 63;
  if (nl >= nrows) return;
  int node = base + nl;
  int fo = lane * VEC;
  float res[VEC];
  if (node < N_NODES) {
    float acc[VEC];
#pragma unroll
    for (int v = 0; v < VEC; ++v) acc[v] = 0.f;
    int e0 = __builtin_amdgcn_readfirstlane(rowptr[node]);
    int e1 = __builtin_amdgcn_readfirstlane(rowptr[node + 1]);
    int e = e0;
    for (; e + 8 <= e1; e += 8) {
      int ss[8]; float nn[8];
#pragma unroll
      for (int j = 0; j < 8; ++j) ss[j] = colidx[e + j];
#pragma unroll
      for (int j = 0; j < 8; ++j) nn[j] = nrm[ss[j]];
      if constexpr (VEC == 2) {
        unsigned int uu[8];
#pragma unroll
        for (int j = 0; j < 8; ++j) uu[j] = *(const unsigned int*)(gh + (size_t)ss[j] * F + fo);
#pragma unroll
        for (int j = 0; j < 8; ++j) {
          acc[0] += bf2f((u16)uu[j]) * nn[j];
          acc[1] += bf2f((u16)(uu[j] >> 16)) * nn[j];
        }
      } else {
        uint2 uu[8];
#pragma unroll
        for (int j = 0; j < 8; ++j) uu[j] = *(const uint2*)(gh + (size_t)ss[j] * F + fo);
#pragma unroll
        for (int j = 0; j < 8; ++j) {
          acc[0] += bf2f((u16)uu[j].x) * nn[j];
          acc[1] += bf2f((u16)(uu[j].x >> 16)) * nn[j];
          acc[2] += bf2f((u16)uu[j].y) * nn[j];
          acc[3] += bf2f((u16)(uu[j].y >> 16)) * nn[j];
        }
      }
    }
    for (; e + 4 <= e1; e += 4) {
      int ss[4]; float nn[4];
#pragma unroll
      for (int j = 0; j < 4; ++j) ss[j] = colidx[e + j];
#pragma unroll
      for (int j = 0; j < 4; ++j) nn[j] = nrm[ss[j]];
      if constexpr (VEC == 2) {
        unsigned int uu[4];
#pragma unroll
        for (int j = 0; j < 4; ++j) uu[j] = *(const unsigned int*)(gh + (size_t)ss[j] * F + fo);
#pragma unroll
        for (int j = 0; j < 4; ++j) {
          acc[0] += bf2f((u16)uu[j]) * nn[j];
          acc[1] += bf2f((u16)(uu[j] >> 16)) * nn[j];
        }
      } else {
        uint2 uu[4];
#pragma unroll
        for (int j = 0; j < 4; ++j) uu[j] = *(const uint2*)(gh + (size_t)ss[j] * F + fo);
#pragma unroll
        for (int j = 0; j < 4; ++j) {
          acc[0] += bf2f((u16)uu[j].x) * nn[j];
          acc[1] += bf2f((u16)(uu[j].x >> 16)) * nn[j];
          acc[2] += bf2f((u16)uu[j].y) * nn[j];
          acc[3] += bf2f((u16)(uu[j].y >> 16)) * nn[j];
        }
      }
    }
    for (; e < e1; ++e) {
      int s = colidx[e];
      float ns = nrm[s];
      const u16* ph = gh + (size_t)s * F + fo;
      if constexpr (VEC == 2) {
        unsigned int uh = *(const unsigned int*)ph;
        acc[0] += bf2f((u16)uh) * ns;
        acc[1] += bf2f((u16)(uh >> 16)) * ns;
      } else {
        uint2 uh = *(const uint2*)ph;
        acc[0] += bf2f((u16)uh.x) * ns;
        acc[1] += bf2f((u16)(uh.x >> 16)) * ns;
        acc[2] += bf2f((u16)uh.y) * ns;
        acc[3] += bf2f((u16)(uh.y >> 16)) * ns;
      }
    }
    float sc2 = alpha * nrm[node];
#pragma unroll
    for (int v = 0; v < VEC; ++v) res[v] = sc2 * acc[v];
  } else {
#pragma unroll
    for (int v = 0; v < VEC; ++v) res[v] = 0.f;
  }
  u16* po = oh + (size_t)nl * F + fo;
  if constexpr (VEC == 2) {
    *(unsigned int*)po = (unsigned int)f2bf(res[0]) | ((unsigned int)f2bf(res[1]) << 16);
  } else {
    uint2 w;
    w.x = (unsigned int)f2bf(res[0]) | ((unsigned int)f2bf(res[1]) << 16);
    w.y = (unsigned int)f2bf(res[2]) | ((unsigned int)f2bf(res[3]) << 16);
    *(uint2*)po = w;
  }
}

// ======== coalesced staging layout (both GEMMs) ========
// LDS tile: [idx][32] u16 -- one 64B line per row/col. Global source is
// pre-swizzled (quarter (tid&3)^((idx>>1)&3)) so 4 consecutive lanes read one
// cache line; ds_read applies the same XOR: slot = kq ^ ((li>>1)&3). 2-way
// bank alias only (free, m136).
//
// ======== 2-buffer, 2-barrier K-step (occupancy-first) ========
// Round 13-15 established: pipeline/drain variants are all equal at 2 blocks/CU
// -- the limiter is resident waves at the barrier rendezvous (Occ 37%).
// 2 LDS buffers halve the footprint: wide 48 KB -> 3 blocks/CU (24 waves),
// BN=128 32 KB -> 4 blocks/CU (32 waves, 100%). Step: counted vmcnt publishes
// stage t -> barrier -> ds_reads -> lgkm drain -> barrier -> stage(t+2) into
// the just-read buffer -> MFMA. Depth in flight unchanged (2 stages).

// ---------------- MFMA GEMM (BN=128) ----------------
template<bool POOL>
__launch_bounds__(512, 4)
__global__ void k_gemm_mfma(const u16* __restrict__ A0, const u16* __restrict__ A1,
                            const u16* __restrict__ A2, int F,
                            const u16* __restrict__ Bth,
                            const float* __restrict__ bias, u16* __restrict__ O,
                            float* __restrict__ hg, const int* __restrict__ gid,
                            int fout, int nrows) {
  __shared__ u16 As[2][128][32];   // 16 KB
  __shared__ u16 Bs[2][128][32];   // 16 KB
  const int tid = threadIdx.x;
  const int lane = tid & 63, wid = tid >> 6;
  const int wm = wid >> 2, wn = wid & 3;          // 2x4 waves, 64x32 each
  const int row0 = blockIdx.y * 128, col0 = blockIdx.x * 128;
  const int K3 = 3 * F;
  const int li = lane & 15, kq = lane >> 4;
  const int sidx = tid >> 2;                      // staged row/col index
  const int skg = (tid & 3) ^ ((sidx >> 1) & 3);  // pre-swizzled 16B quarter
  const size_t dso = (size_t)wid * 512;           // wave-uniform LDS base (u16)
  const int slot = (kq ^ ((li >> 1) & 3)) * 8;    // ds_read-side swizzle

  auto stage = [&](int t, int b) {
    int k0 = t * 32;
    const u16* S; int kk;
    if (k0 < F)          { S = A0; kk = k0; }
    else if (k0 < 2 * F) { S = A1; kk = k0 - F; }
    else                 { S = A2; kk = k0 - 2 * F; }
    glds16(S + (size_t)(row0 + sidx) * F + (kk + skg * 8), &As[b][0][0] + dso);
    glds16(Bth + (size_t)(col0 + sidx) * K3 + (k0 + skg * 8), &Bs[b][0][0] + dso);
  };

  f32x4 acc[4][2];
#pragma unroll
  for (int m = 0; m < 4; ++m)
#pragma unroll
    for (int n = 0; n < 2; ++n) acc[m][n] = (f32x4){0.f, 0.f, 0.f, 0.f};

  const int NT = K3 / 32;                         // 12 or 24
  stage(0, 0);
  stage(1, 1);
  for (int t = 0; t < NT; ++t) {
    if (t + 1 < NT) asm volatile("s_waitcnt vmcnt(2)" ::: "memory");
    else            asm volatile("s_waitcnt vmcnt(0)" ::: "memory");
    __builtin_amdgcn_sched_barrier(0);
    __builtin_amdgcn_s_barrier();                 // everyone's stage-t visible
    const int cb = t & 1;
    s16x8 a[4], bh[2];
#pragma unroll
    for (int m = 0; m < 4; ++m)
      a[m] = *(const s16x8*)&As[cb][wm * 64 + m * 16 + li][slot];
#pragma unroll
    for (int n = 0; n < 2; ++n)
      bh[n] = *(const s16x8*)&Bs[cb][wn * 32 + n * 16 + li][slot];
    asm volatile("s_waitcnt lgkmcnt(0)" ::: "memory");  // reads done (2-buf req.)
    __builtin_amdgcn_sched_barrier(0);            // rule 18
    __builtin_amdgcn_s_barrier();                 // all waves done reading cb
    if (t + 2 < NT) stage(t + 2, cb);             // refill just-read buffer
    __builtin_amdgcn_s_setprio(1);
#pragma unroll
    for (int m = 0; m < 4; ++m)
#pragma unroll
      for (int n = 0; n < 2; ++n)
        acc[m][n] = __builtin_amdgcn_mfma_f32_16x16x32_bf16(a[m], bh[n], acc[m][n], 0, 0, 0);
    __builtin_amdgcn_s_setprio(0);
  }

  if (!POOL) {
#pragma unroll
    for (int m = 0; m < 4; ++m) {
      int rbase = row0 + wm * 64 + m * 16 + kq * 4;
#pragma unroll
      for (int n = 0; n < 2; ++n) {
        int col = col0 + wn * 32 + n * 16 + li;
        float bi = bias[col];
#pragma unroll
        for (int r2 = 0; r2 < 4; ++r2) {
          int rr = rbase + r2;
          if (rr < nrows)
            O[(size_t)rr * fout + col] = f2bf(fmaxf(acc[m][n][r2] + bi, 0.f));
        }
      }
    }
  } else {
#pragma unroll
    for (int m = 0; m < 4; ++m) {
      int rbase = row0 + wm * 64 + m * 16 + kq * 4;
      int g4[4];
#pragma unroll
      for (int r2 = 0; r2 < 4; ++r2) {
        int rr = rbase + r2;
        g4[r2] = (rr < nrows) ? gid[rr] : -1;
      }
#pragma unroll
      for (int n = 0; n < 2; ++n) {
        int col = col0 + wn * 32 + n * 16 + li;
        float bi = bias[col];
        float sum = 0.f; int curg = g4[0];
#pragma unroll
        for (int r2 = 0; r2 < 4; ++r2) {
          if (g4[r2] != curg) {
            if (curg >= 0) atomicAdd(&hg[curg * 512 + col], sum);
            sum = 0.f; curg = g4[r2];
          }
          if (g4[r2] >= 0) sum += fmaxf(acc[m][n][r2] + bi, 0.f);
        }
        if (curg >= 0) atomicAdd(&hg[curg * 512 + col], sum);
      }
    }
  }
}

// ---------------- MFMA GEMM wide (BN=256) ----------------
template<bool POOL>
__launch_bounds__(512, 4)
__global__ void k_gemm_wide(const u16* __restrict__ A0, const u16* __restrict__ A1,
                            const u16* __restrict__ A2, int F,
                            const u16* __restrict__ Bth,
                            const float* __restrict__ bias, u16* __restrict__ O,
                            float* __restrict__ hg, const int* __restrict__ gid,
                            int fout, int nrows) {
  __shared__ u16 As[2][128][32];   // 16 KB
  __shared__ u16 Bs[2][256][32];   // 32 KB
  const int tid = threadIdx.x;
  const int lane = tid & 63, wid = tid >> 6;
  const int wm = wid >> 2, wn = wid & 3;          // 2x4 waves, 64x64 each
  const int row0 = blockIdx.y * 128, col0 = blockIdx.x * 256;
  const int K3 = 3 * F;
  const int li = lane & 15, kq = lane >> 4;
  const int sidx = tid >> 2;
  const int skg = (tid & 3) ^ ((sidx >> 1) & 3);
  const size_t dsoA = (size_t)wid * 512;          // wave-uniform (u16)
  const int slot = (kq ^ ((li >> 1) & 3)) * 8;

  auto stage = [&](int t, int b) {
    int k0 = t * 32;
    const u16* S; int kk;
    if (k0 < F)          { S = A0; kk = k0; }
    else if (k0 < 2 * F) { S = A1; kk = k0 - F; }
    else                 { S = A2; kk = k0 - 2 * F; }
    glds16(S + (size_t)(row0 + sidx) * F + (kk + skg * 8), &As[b][0][0] + dsoA);
#pragma unroll
    for (int r = 0; r < 2; ++r) {
      int s = r * 512 + tid;
      int col = s >> 2;
      int kgB = (s & 3) ^ ((col >> 1) & 3);
      glds16(Bth + (size_t)(col0 + col) * K3 + (k0 + kgB * 8),
             &Bs[b][0][0] + (size_t)(r * 512 + wid * 64) * 8);
    }
  };

  f32x4 acc[4][4];
#pragma unroll
  for (int m = 0; m < 4; ++m)
#pragma unroll
    for (int n = 0; n < 4; ++n) acc[m][n] = (f32x4){0.f, 0.f, 0.f, 0.f};

  const int NT = K3 / 32;                         // 12 or 24
  stage(0, 0);
  stage(1, 1);
  for (int t = 0; t < NT; ++t) {
    if (t + 1 < NT) asm volatile("s_waitcnt vmcnt(3)" ::: "memory");
    else            asm volatile("s_waitcnt vmcnt(0)" ::: "memory");
    __builtin_amdgcn_sched_barrier(0);
    __builtin_amdgcn_s_barrier();                 // everyone's stage-t visible
    const int cb = t & 1;
    s16x8 a[4], b[4];
#pragma unroll
    for (int m = 0; m < 4; ++m)
      a[m] = *(const s16x8*)&As[cb][wm * 64 + m * 16 + li][slot];
#pragma unroll
    for (int n = 0; n < 4; ++n)
      b[n] = *(const s16x8*)&Bs[cb][wn * 64 + n * 16 + li][slot];
    asm volatile("s_waitcnt lgkmcnt(0)" ::: "memory");  // reads done (2-buf req.)
    __builtin_amdgcn_sched_barrier(0);            // rule 18
    __builtin_amdgcn_s_barrier();                 // all waves done reading cb
    if (t + 2 < NT) stage(t + 2, cb);             // refill just-read buffer
    __builtin_amdgcn_s_setprio(1);
#pragma unroll
    for (int m = 0; m < 4; ++m)
#pragma unroll
      for (int n = 0; n < 4; ++n)
        acc[m][n] = __builtin_amdgcn_mfma_f32_16x16x32_bf16(a[m], b[n], acc[m][n], 0, 0, 0);
    __builtin_amdgcn_s_setprio(0);
  }

  if (!POOL) {
#pragma unroll
    for (int m = 0; m < 4; ++m) {
      int rbase = row0 + wm * 64 + m * 16 + kq * 4;
#pragma unroll
      for (int n = 0; n < 4; ++n) {
        int col = col0 + wn * 64 + n * 16 + li;
        float bi = bias[col];
#pragma unroll
        for (int r2 = 0; r2 < 4; ++r2) {
          int rr = rbase + r2;
          if (rr < nrows)
            O[(size_t)rr * fout + col] = f2bf(fmaxf(acc[m][n][r2] + bi, 0.f));
        }
      }
    }
  } else {
#pragma unroll
    for (int m = 0; m < 4; ++m) {
      int rbase = row0 + wm * 64 + m * 16 + kq * 4;
      int g4[4];
#pragma unroll
      for (int r2 = 0; r2 < 4; ++r2) {
        int rr = rbase + r2;
        g4[r2] = (rr < nrows) ? gid[rr] : -1;
      }
#pragma unroll
      for (int n = 0; n < 4; ++n) {
        int col = col0 + wn * 64 + n * 16 + li;
        float bi = bias[col];
        float sum = 0.f; int curg = g4[0];
#pragma unroll
        for (int r2 = 0; r2 < 4; ++r2) {
          if (g4[r2] != curg) {
            if (curg >= 0) atomicAdd(&hg[curg * 512 + col], sum);
            sum = 0.f; curg = g4[r2];
          }
          if (g4[r2] >= 0) sum += fmaxf(acc[m][n][r2] + bi, 0.f);
        }
        if (curg >= 0) atomicAdd(&hg[curg * 512 + col], sum);
      }
    }
  }
}

// ---------------- MLP head ----------------
__global__ void k_mlp(const float* __restrict__ hg, const float* __restrict__ Wm1,
                      const float* __restrict__ bm1, const float* __restrict__ Wm2,
                      const float* __restrict__ bm2, float* __restrict__ outp) {
  __shared__ float lh[512];
  __shared__ float lt[512];
  int g = blockIdx.x, t = threadIdx.x;
  lh[t] = hg[g * 512 + t];
  __syncthreads();
  float s = bm1[t];
  for (int k = 0; k < 512; ++k) s += lh[k] * Wm1[k * 512 + t];
  lt[t] = fmaxf(s, 0.f);
  __syncthreads();
  if (t < 10) {
    float s2 = bm2[t];
    for (int j = 0; j < 512; ++j) s2 += lt[j] * Wm2[j * 10 + t];
    outp[g * 10 + t] = s2;
  }
}

// ---------------- launch ----------------
extern "C" void kernel_launch(void* const* d_in, const int* in_sizes, int n_in,
                              void* d_out, int out_size, void* d_ws, size_t ws_size,
                              hipStream_t stream) {
  (void)in_sizes; (void)n_in; (void)out_size;
  const float* signal = (const float*)d_in[0];
  const float* W0 = (const float*)d_in[1];  const float* b0 = (const float*)d_in[2];
  const float* W1 = (const float*)d_in[3];  const float* b1 = (const float*)d_in[4];
  const float* W2 = (const float*)d_in[5];  const float* b2 = (const float*)d_in[6];
  const float* W3 = (const float*)d_in[7];  const float* b3 = (const float*)d_in[8];
  const float* Wm1 = (const float*)d_in[9];  const float* bm1 = (const float*)d_in[10];
  const float* Wm2 = (const float*)d_in[11]; const float* bm2 = (const float*)d_in[12];
  const int* src = (const int*)d_in[13];
  const int* dst = (const int*)d_in[14];
  const int* gid = (const int*)d_in[15];
  float* outp = (float*)d_out;

  char* ws = (char*)d_ws;
  size_t off = 0;
  auto alloc = [&](size_t b) -> void* {
    void* p = ws + off;
    off = (off + b + 255) & ~(size_t)255;
    return p;
  };
  // fixed footprint ~130 MB (+51 MB QY when ws allows; proven in rounds 11-14)
  int* degi    = (int*)alloc((size_t)N_NODES * 4);
  float* nrm   = (float*)alloc((size_t)N_NODES * 4);
  int* rowptr  = (int*)alloc((size_t)(N_NODES + 1) * 4);
  int* cursor  = (int*)alloc((size_t)N_NODES * 4);
  int* bsum    = (int*)alloc((size_t)SCAN_G * 4);
  int* boff    = (int*)alloc((size_t)SCAN_G * 4);
  int* colidx  = (int*)alloc((size_t)N_EDGES * 4);
  float* hg    = (float*)alloc((size_t)N_GRAPH * 512 * 4);
  u16* Wth0 = (u16*)alloc((size_t)384 * 128 * 2);
  u16* Wth1 = (u16*)alloc((size_t)384 * 128 * 2);
  u16* Wth2 = (u16*)alloc((size_t)384 * 256 * 2);
  u16* Wth3 = (u16*)alloc((size_t)768 * 512 * 2);
  u16* QA = (u16*)alloc((size_t)PAD_N * 256 * 2);   // L1 out / L2 in / L3 out / L4 in
  u16* QB = (u16*)alloc((size_t)PAD_N * 128 * 2);   // sig / L2 out / L3 in / L4 Y-chunk
  u16* QX = (u16*)alloc((size_t)PAD_N * 256 * 2);   // X1 (+Y in 2nd half for F=128)
  const size_t yneed = (size_t)PAD_N * 256 * 2;
  u16* QY = nullptr;
  if (ws_size > off && ws_size - off >= yneed + 512) QY = (u16*)alloc(yneed);

  hipMemsetAsync(degi, 0, (size_t)N_NODES * 4, stream);
  hipMemsetAsync(cursor, 0, (size_t)N_NODES * 4, stream);
  hipMemsetAsync(hg, 0, (size_t)N_GRAPH * 512 * 4, stream);

  k_deg<<<(N_EDGES + 255) / 256, 256, 0, stream>>>(dst, degi);
  k_norm<<<(N_NODES + 255) / 256, 256, 0, stream>>>(degi, nrm);
  k_scan1<<<SCAN_G, SCAN_B, 0, stream>>>(degi, rowptr, bsum);
  k_scan2<<<1, 128, 0, stream>>>(bsum, boff, rowptr);
  k_scan3<<<SCAN_G, SCAN_B, 0, stream>>>(rowptr, boff);
  k_scatter<<<(N_EDGES + 255) / 256, 256, 0, stream>>>(src, dst, rowptr, cursor, colidx);

  k_wsplit<<<(384 * 128 + 255) / 256, 256, 0, stream>>>(W0, Wth0, 128, 128);
  k_wsplit<<<(384 * 128 + 255) / 256, 256, 0, stream>>>(W1, Wth1, 128, 128);
  k_wsplit<<<(384 * 256 + 255) / 256, 256, 0, stream>>>(W2, Wth2, 128, 256);
  k_wsplit<<<(768 * 512 + 255) / 256, 256, 0, stream>>>(W3, Wth3, 256, 512);
  k_sigcast<<<(PAD_N * 128 + 255) / 256, 256, 0, stream>>>(signal, QB);

  const int gfull = (PAD_N + 3) / 4;   // ahat grid, 4 nodes per 256-thread block

  // ---- layers 1-2 (F=128, fout=128) ----
  u16* X1h = QX;
  u16* Yh  = QX + (size_t)PAD_N * 128;
  auto layer128 = [&](const u16* in, const u16* wth, const float* bias, u16* outb) {
    k_ahat_bf<2><<<gfull, 256, 0, stream>>>(in,  nrm, rowptr, colidx, X1h, 128, 0, PAD_N, -1.f);
    k_ahat_bf<2><<<gfull, 256, 0, stream>>>(X1h, nrm, rowptr, colidx, Yh,  128, 0, PAD_N,  1.f);
    dim3 gg(1, PAD_N / 128);
    k_gemm_mfma<false><<<gg, 512, 0, stream>>>(in, X1h, Yh, 128, wth, bias,
                                               outb, nullptr, nullptr, 128, N_NODES);
  };
  layer128(QB, Wth0, b0, QA);
  layer128(QA, Wth1, b1, QB);

  // ---- layer 3 (F=128, fout=256): wide kernel, single col-block ----
  k_ahat_bf<2><<<gfull, 256, 0, stream>>>(QB,  nrm, rowptr, colidx, X1h, 128, 0, PAD_N, -1.f);
  k_ahat_bf<2><<<gfull, 256, 0, stream>>>(X1h, nrm, rowptr, colidx, Yh,  128, 0, PAD_N,  1.f);
  {
    dim3 gg(1, PAD_N / 128);
    k_gemm_wide<false><<<gg, 512, 0, stream>>>(QB, X1h, Yh, 128, Wth2, b2,
                                               QA, nullptr, nullptr, 256, N_NODES);
  }

  // ---- layer 4 (F=256, fout=512, pooled) ----
  k_ahat_bf<4><<<gfull, 256, 0, stream>>>(QA, nrm, rowptr, colidx, QX, 256, 0, PAD_N, -1.f);
  if (QY != nullptr) {
    k_ahat_bf<4><<<gfull, 256, 0, stream>>>(QX, nrm, rowptr, colidx, QY, 256, 0, PAD_N, 1.f);
    dim3 gg(2, PAD_N / 128);
    k_gemm_wide<true><<<gg, 512, 0, stream>>>(QA, QX, QY, 256, Wth3, b3,
                                              nullptr, hg, gid, 512, N_NODES);
  } else {
    const int CH4 = 50048;
    for (int base = 0; base < N_NODES; base += CH4) {
      int nr = (N_NODES - base < CH4) ? (N_NODES - base) : CH4;
      k_ahat_bf<4><<<(nr + 3) / 4, 256, 0, stream>>>(QX, nrm, rowptr, colidx, QB,
                                                     256, base, nr, 1.f);
      dim3 gg(4, (nr + 127) / 128);
      k_gemm_mfma<true><<<gg, 512, 0, stream>>>(
          QA + (size_t)base * 256, QX + (size_t)base * 256, QB, 256,
          Wth3, b3, nullptr, hg, gid + base, 512, nr);
    }
  }

  k_mlp<<<N_GRAPH, 512, 0, stream>>>(hg, Wm1, bm1, Wm2, bm2, outp);
}